// Round 1
// baseline (334.621 us; speedup 1.0000x reference)
//
#include <hip/hip_runtime.h>
#include <hip/hip_bf16.h>

#define NN 262144
#define NCC 65536
#define DD 256

typedef __bf16 bf16x8 __attribute__((ext_vector_type(8)));
typedef float f32x4 __attribute__((ext_vector_type(4)));

// ---------------- flags ----------------
__global__ void k_zero16(unsigned char* p, int n16) {
    int i = blockIdx.x * blockDim.x + threadIdx.x;
    if (i < n16) ((uint4*)p)[i] = make_uint4(0u, 0u, 0u, 0u);
}

__global__ void k_setflags(const int* __restrict__ idxp, const int* __restrict__ idxc,
                           unsigned char* fp, unsigned char* fc) {
    int j = blockIdx.x * blockDim.x + threadIdx.x;
    if (j < NCC) { fp[idxp[j]] = 1; fc[idxc[j]] = 1; }
}

// ---------------- precompute Mt[o][g] = sum_k W_fuse[o][seg*256+k] * w_seg[m][k], g=seg*256+m ----------------
__global__ __launch_bounds__(256) void k_precompute(const float* __restrict__ w_orig,
                                                    const float* __restrict__ w_prop,
                                                    const float* __restrict__ w_ctx,
                                                    const float* __restrict__ W_fuse,
                                                    __bf16* __restrict__ Mt) {
    int b = blockIdx.x;                 // 48 blocks: 3 segs x 4 otiles x 4 mtiles
    int seg = b >> 4, rem = b & 15;
    int ot = rem >> 2, mt = rem & 3;
    const float* wseg = seg == 0 ? w_orig : (seg == 1 ? w_prop : w_ctx);
    __shared__ float Wl[64 * 65];
    __shared__ float wl[64 * 65];
    int t = threadIdx.x;
    int to = (t & 15) * 4, tm = (t >> 4) * 4;
    float acc[4][4] = {};
    for (int kc = 0; kc < 4; ++kc) {
        __syncthreads();
        for (int i = 0; i < 16; ++i) {
            int f = i * 256 + t;        // 0..4095
            int row = f >> 6, col = f & 63;
            Wl[row * 65 + col] = W_fuse[(size_t)(ot * 64 + row) * 768 + seg * 256 + kc * 64 + col];
            wl[row * 65 + col] = wseg[(size_t)(mt * 64 + row) * 256 + kc * 64 + col];
        }
        __syncthreads();
        for (int k = 0; k < 64; ++k) {
            float wo[4], wm2[4];
#pragma unroll
            for (int i = 0; i < 4; ++i) wo[i] = Wl[(to + i) * 65 + k];
#pragma unroll
            for (int j = 0; j < 4; ++j) wm2[j] = wl[(tm + j) * 65 + k];
#pragma unroll
            for (int i = 0; i < 4; ++i)
#pragma unroll
                for (int j = 0; j < 4; ++j) acc[i][j] += wo[i] * wm2[j];
        }
    }
    for (int i = 0; i < 4; ++i)
        for (int j = 0; j < 4; ++j) {
            int o = ot * 64 + to + i;
            int g = seg * 256 + mt * 64 + tm + j;
            Mt[(size_t)o * 768 + g] = (__bf16)acc[i][j];
        }
}

// ---------------- main gathered GEMM + epilogue + scatter ----------------
// tile: 64 rows x 256 cols, 8 waves (2x4), wave tile 32x64, K=768 in 12 chunks of 64
__global__ __launch_bounds__(512, 4) void k_gemm(const float* __restrict__ hp,
                                                 const float* __restrict__ hc,
                                                 const float* __restrict__ horig,
                                                 const __bf16* __restrict__ Mt,
                                                 const float* __restrict__ bfuse,
                                                 const float* __restrict__ bias,
                                                 const int* __restrict__ idxp,
                                                 const int* __restrict__ idxc,
                                                 float* __restrict__ out0,
                                                 float* __restrict__ out1) {
    __shared__ __bf16 Al[64 * 64];    // [row][k] swizzled, 8KB
    __shared__ __bf16 Bl[256 * 64];   // [o][k]  swizzled, 32KB  (holds B^T chunk)
    int t = threadIdx.x;
    int jbase = blockIdx.x * 64;
    int lane = t & 63, wid = t >> 6;
    int wm = wid >> 2, wn = wid & 3;

    // A staging assignment: thread -> (row, k-slot of 8 floats)
    int ar = t >> 3;
    int aslot = t & 7;
    int jr = jbase + ar;
    const float* rowp0 = horig + (size_t)jr * 256;
    const float* rowp1 = hp + (size_t)idxp[jr] * 256;
    const float* rowp2 = hc + (size_t)idxc[jr] * 256;

    // B staging assignment: thread -> (o, half of 64-k chunk)
    int bo = t >> 1;
    int bkp = t & 1;

    f32x4 acc[2][4] = {};

    for (int c = 0; c < 12; ++c) {
        if (c) __syncthreads();
        // stage A chunk: 64 rows x 64 k (from seg source, f32 -> bf16)
        {
            int seg = c >> 2, ko = (c & 3) * 64;
            const float* src = (seg == 0 ? rowp0 : (seg == 1 ? rowp1 : rowp2)) + ko + aslot * 8;
            float4 v0 = *(const float4*)(src);
            float4 v1 = *(const float4*)(src + 4);
            bf16x8 w;
            w[0] = (__bf16)v0.x; w[1] = (__bf16)v0.y; w[2] = (__bf16)v0.z; w[3] = (__bf16)v0.w;
            w[4] = (__bf16)v1.x; w[5] = (__bf16)v1.y; w[6] = (__bf16)v1.z; w[7] = (__bf16)v1.w;
            *(bf16x8*)&Al[ar * 64 + ((aslot ^ (ar & 7)) << 3)] = w;
        }
        // stage B chunk: 256 o x 64 k straight copy from Mt (already transposed)
        {
            const __bf16* src = Mt + (size_t)bo * 768 + c * 64 + bkp * 32;
#pragma unroll
            for (int i = 0; i < 4; ++i) {
                bf16x8 v = *(const bf16x8*)(src + i * 8);
                int slot = bkp * 4 + i;
                *(bf16x8*)&Bl[bo * 64 + ((slot ^ (bo & 7)) << 3)] = v;
            }
        }
        __syncthreads();
#pragma unroll
        for (int ks = 0; ks < 2; ++ks) {
            bf16x8 af[2], bfr[4];
            int kslot = ks * 4 + (lane >> 4);
#pragma unroll
            for (int mi = 0; mi < 2; ++mi) {
                int r = wm * 32 + mi * 16 + (lane & 15);
                af[mi] = *(const bf16x8*)&Al[r * 64 + ((kslot ^ (r & 7)) << 3)];
            }
#pragma unroll
            for (int ni = 0; ni < 4; ++ni) {
                int o = wn * 64 + ni * 16 + (lane & 15);
                bfr[ni] = *(const bf16x8*)&Bl[o * 64 + ((kslot ^ (o & 7)) << 3)];
            }
#pragma unroll
            for (int mi = 0; mi < 2; ++mi)
#pragma unroll
                for (int ni = 0; ni < 4; ++ni)
                    acc[mi][ni] = __builtin_amdgcn_mfma_f32_16x16x32_bf16(af[mi], bfr[ni], acc[mi][ni], 0, 0, 0);
        }
    }

    // epilogue: tanh(acc + b_fuse) + bias, scatter rows into both outputs
    float bfv[4], biv[4];
#pragma unroll
    for (int ni = 0; ni < 4; ++ni) {
        int o = wn * 64 + ni * 16 + (lane & 15);
        bfv[ni] = bfuse[o];
        biv[ni] = bias[o];
    }
#pragma unroll
    for (int mi = 0; mi < 2; ++mi) {
#pragma unroll
        for (int rr = 0; rr < 4; ++rr) {
            int j = jbase + wm * 32 + mi * 16 + (lane >> 4) * 4 + rr;
            int gp = idxp[j];
            int gc = idxc[j];
#pragma unroll
            for (int ni = 0; ni < 4; ++ni) {
                int o = wn * 64 + ni * 16 + (lane & 15);
                float v = tanhf(acc[mi][ni][rr] + bfv[ni]) + biv[ni];
                out0[(size_t)gp * 256 + o] = v;
                out1[(size_t)gc * 256 + o] = v;
            }
        }
    }
}

// ---------------- masked row copy: wave per row, skip common rows ----------------
__global__ __launch_bounds__(256) void k_copy(const float* __restrict__ hp,
                                              const float* __restrict__ hc,
                                              const unsigned char* __restrict__ fp,
                                              const unsigned char* __restrict__ fc,
                                              float* __restrict__ out0,
                                              float* __restrict__ out1) {
    int wid = (blockIdx.x * blockDim.x + threadIdx.x) >> 6;
    int lane = threadIdx.x & 63;
    int nw = (gridDim.x * blockDim.x) >> 6;
    for (int R = wid; R < 2 * NN; R += nw) {
        int tbl = (R >= NN);
        int r = tbl ? (R - NN) : R;
        unsigned char f = tbl ? fc[r] : fp[r];
        if (!f) {
            const float* s = (tbl ? hc : hp) + (size_t)r * 256 + lane * 4;
            float* d = (tbl ? out1 : out0) + (size_t)r * 256 + lane * 4;
            *(float4*)d = *(const float4*)s;
        }
    }
}

extern "C" void kernel_launch(void* const* d_in, const int* in_sizes, int n_in,
                              void* d_out, int out_size, void* d_ws, size_t ws_size,
                              hipStream_t stream) {
    const float* hp     = (const float*)d_in[0];
    const float* hc     = (const float*)d_in[1];
    const float* horig  = (const float*)d_in[2];
    const float* w_orig = (const float*)d_in[3];
    const float* w_prop = (const float*)d_in[4];
    const float* w_ctx  = (const float*)d_in[5];
    const float* W_fuse = (const float*)d_in[6];
    const float* bfuse  = (const float*)d_in[7];
    const float* bias   = (const float*)d_in[8];
    const int* idxp     = (const int*)d_in[9];
    const int* idxc     = (const int*)d_in[10];
    float* out0 = (float*)d_out;
    float* out1 = out0 + (size_t)NN * DD;

    char* ws = (char*)d_ws;
    __bf16* Mt = (__bf16*)ws;                              // 256*768*2 = 393216 B
    unsigned char* fp = (unsigned char*)(ws + 393216);     // N bytes
    unsigned char* fc = fp + NN;                           // N bytes

    // zero both flag arrays (2N bytes, contiguous)
    k_zero16<<<(2 * NN / 16 + 255) / 256, 256, 0, stream>>>(fp, 2 * NN / 16);
    k_setflags<<<NCC / 256, 256, 0, stream>>>(idxp, idxc, fp, fc);
    k_precompute<<<48, 256, 0, stream>>>(w_orig, w_prop, w_ctx, W_fuse, Mt);
    k_gemm<<<NCC / 64, 512, 0, stream>>>(hp, hc, horig, Mt, bfuse, bias, idxp, idxc, out0, out1);
    k_copy<<<4096, 256, 0, stream>>>(hp, hc, fp, fc, out0, out1);
}